// Round 2
// baseline (143.681 us; speedup 1.0000x reference)
//
#include <hip/hip_runtime.h>
#include <stdint.h>

#define B 4
#define S 2048
#define E 2048
#define H 128

typedef _Float16 f16;
typedef _Float16 half4 __attribute__((ext_vector_type(4)));
typedef _Float16 half8 __attribute__((ext_vector_type(8)));
typedef float f32x4 __attribute__((ext_vector_type(4)));

// MFMA 16x16x32 f16 (m89/m91):
//   A-frag: lane(quad,lx) holds A[m=lx][k=quad*8+j]
//   B-frag: lane(quad,lx) holds B[k=quad*8+j][n=lx]
//   C/D  : lane(quad,lx) holds D[row=quad*4+reg][col=lx]
// FRAG-LINEAR GLOBAL: frag f = 512 f16 at dst[f*512 + lane*8 .. +8]:
// every frag load/store is one coalesced 1 KB b128 per wave.

// ---------------------------------------------------------------------------
// Kernel 0: W matrices fp32 [128][2048] -> frag-linear f16.
//   WQ -> Wf frag = kc*16 + rt ; WK -> +8 ; WV -> Vf frag = kc*8 + rt
// ---------------------------------------------------------------------------
__global__ __launch_bounds__(256) void cvt_w_kernel(
    const float* __restrict__ WQ, const float* __restrict__ WK,
    const float* __restrict__ WV,
    f16* __restrict__ Wf, f16* __restrict__ Vf)
{
    __shared__ __align__(16) f16 LT[4 * 512];
    const int t   = threadIdx.x;
    const int cc  = blockIdx.x;
    const int rt  = blockIdx.y;
    const int mat = blockIdx.z;
    const float* src = (mat == 0) ? WQ : (mat == 1) ? WK : WV;

#pragma unroll
    for (int i = 0; i < 2; ++i) {
        const int idx = i * 256 + t;
        const int row = idx >> 5;
        const int c4  = idx & 31;
        float4 v = ((const float4*)src)[(size_t)(rt * 16 + row) * (E / 4) + cc * 32 + c4];
        const int e0   = c4 * 4;
        const int kcl  = e0 >> 5;
        const int quad = (e0 >> 3) & 3;
        const int j    = e0 & 7;
        half4 hv;
        hv[0] = (f16)v.x; hv[1] = (f16)v.y; hv[2] = (f16)v.z; hv[3] = (f16)v.w;
        *(half4*)&LT[(kcl * 64 + quad * 16 + row) * 8 + j] = hv;
    }
    __syncthreads();

    const half8 val = *(const half8*)&LT[t * 8];
    const int kcg = cc * 4 + (t >> 6);
    const int ln  = t & 63;
    if (mat == 2) *(half8*)&Vf[((size_t)kcg * 8  + rt)           * 512 + ln * 8] = val;
    else          *(half8*)&Wf[((size_t)kcg * 16 + rt + mat * 8) * 512 + ln * 8] = val;
}

// ---------------------------------------------------------------------------
// Kernel 1 (v3): Q,K projection. 256 blocks x 1024 thr, 32 rows/block.
// K pipelined in 4 groups of 16 kc; 2 x 32 KB LDS double buffer:
//   issue global loads for g+1  ->  compute g  ->  barrier  ->
//   LDS-write g+1  ->  barrier.
// Staging (HBM BW-bound, ~2.5us/group) overlaps the MFMA k-loop.
// Wf walk rotated within-group per block to de-phase the L2 hotspot.
// ---------------------------------------------------------------------------
__global__ __launch_bounds__(1024, 4) void proj_kernel(
    const float4* __restrict__ X,      // [B*S][E/4] fp32
    const f16* __restrict__ Wf,
    f16* __restrict__ Qf, f16* __restrict__ Kf)
{
    __shared__ __align__(16) f16 XA[2 * 2048 * 8];   // 64 KB: two 32 KB bufs
    const int t    = threadIdx.x;
    const int w    = t >> 6;
    const int lane = t & 63;
    const int quad = lane >> 4;
    const int lx   = lane & 15;
    const int r0   = blockIdx.x * 32;
    const int rot  = blockIdx.x & 15;

    float4 xv[4];

    // issue global loads for group g (wave = 2 KB contiguous within a row)
    auto stage_load = [&](int g) {
#pragma unroll
        for (int i = 0; i < 2; ++i) {
            const int p   = i * 1024 + t;
            const int row = p >> 6;
            const int c42 = p & 63;
            const float4* xp = &X[(size_t)(r0 + row) * (E / 4) + g * 128 + c42 * 2];
            xv[i * 2]     = xp[0];
            xv[i * 2 + 1] = xp[1];
        }
    };
    // convert + swizzled frag-linear LDS write into buf (g&1)
    auto stage_write = [&](int g) {
        f16* buf = &XA[(size_t)(g & 1) * 2048 * 8];
#pragma unroll
        for (int i = 0; i < 2; ++i) {
            const int p   = i * 1024 + t;
            const int row = p >> 6;
            const int c42 = p & 63;
            const int kcl = c42 >> 2;
            const int qs  = c42 & 3;
            const int rt  = row >> 4;
            const int m   = row & 15;
            const int mp  = m ^ ((qs << 1) | (kcl & 1));      // bank swizzle
            half8 hv;
            hv[0] = (f16)xv[i * 2].x;     hv[1] = (f16)xv[i * 2].y;
            hv[2] = (f16)xv[i * 2].z;     hv[3] = (f16)xv[i * 2].w;
            hv[4] = (f16)xv[i * 2 + 1].x; hv[5] = (f16)xv[i * 2 + 1].y;
            hv[6] = (f16)xv[i * 2 + 1].z; hv[7] = (f16)xv[i * 2 + 1].w;
            *(half8*)&buf[(size_t)(kcl * 128 + rt * 64 + qs * 16 + mp) * 8] = hv;
        }
    };

    f32x4 C0 = f32x4{0.f, 0.f, 0.f, 0.f};
    f32x4 C1 = f32x4{0.f, 0.f, 0.f, 0.f};
    const f16* wbase = &Wf[(size_t)w * 512 + lane * 8];     // frag kc*16 + w

    stage_load(0);
    stage_write(0);
    __syncthreads();

    for (int g = 0; g < 4; ++g) {
        if (g < 3) stage_load(g + 1);                       // overlap with MFMA
        const f16* buf = &XA[(size_t)(g & 1) * 2048 * 8];
#pragma unroll 8
        for (int kcl = 0; kcl < 16; ++kcl) {
            const int kcl2 = (kcl + rot) & 15;
            const int kc   = g * 16 + kcl2;
            const int lxs  = lx ^ ((quad << 1) | (kcl2 & 1));
            half8 b  = *(const half8*)&wbase[(size_t)kc * 16 * 512];      // L2
            half8 a0 = *(const half8*)&buf[(size_t)(kcl2 * 128      + quad * 16 + lxs) * 8];
            half8 a1 = *(const half8*)&buf[(size_t)(kcl2 * 128 + 64 + quad * 16 + lxs) * 8];
            C0 = __builtin_amdgcn_mfma_f32_16x16x32_f16(a0, b, C0, 0, 0, 0);
            C1 = __builtin_amdgcn_mfma_f32_16x16x32_f16(a1, b, C1, 0, 0, 0);
        }
        __syncthreads();                 // buf[g&1] reads done
        if (g < 3) {
            stage_write(g + 1);          // into buf[(g+1)&1] (free since g-1)
            __syncthreads();
        }
    }

    // ---- epilogue: C -> LT (target frag layout, reuse XA) -> global ----
    f16* LT = XA;                         // 16 frags = 16 KB (buf0, free)
    {
        const int qt2 = (w & 1) * 2 + (lx >> 3);
        const int jt  = lx & 7;
        const int fl  = w >> 1;           // 0..7: (mat,hc)
#pragma unroll
        for (int reg = 0; reg < 4; ++reg) {
            LT[(size_t)((fl      * 64) + qt2 * 16 + quad * 4 + reg) * 8 + jt] = (f16)C0[reg];
            LT[(size_t)(((fl + 8) * 64) + qt2 * 16 + quad * 4 + reg) * 8 + jt] = (f16)C1[reg];
        }
    }
    __syncthreads();
    {
        const int f  = t >> 6;            // 0..15
        const int ln = t & 63;
        const half8 v = *(const half8*)&LT[(size_t)f * 512 + ln * 8];
        const int rt  = f >> 3;
        const int hc  = f & 3;
        const int mat = (f >> 2) & 1;
        f16* dst = mat ? Kf : Qf;
        *(half8*)&dst[((size_t)(blockIdx.x * 2 + rt) * 4 + hc) * 512 + ln * 8] = v;
    }
}

// ---------------------------------------------------------------------------
// Kernel 2 (v2): attention. 512 blocks x 512 thr (2 blocks/CU).
// Register-pressure-shaped chunk loop (peak live ~123 <= 128, no spill):
//   QK (setprio) -> kb prefetch for c+2 (same regs, hides K L2 latency)
//   -> vb half 1 -> exp/PL -> PV 0..3 -> vb half 2 -> PV 4..7.
// Epilogue: 3-barrier tree O-combine (was 8-step serial).
// ---------------------------------------------------------------------------
__global__ __launch_bounds__(512, 4) void attn_kernel(
    const f16* __restrict__ Qf, const f16* __restrict__ Kf,
    const f16* __restrict__ Vf,
    float* __restrict__ out)
{
    __shared__ __align__(16) f16 PL[8 * 512];
    __shared__ float Obuf[4][16][132];
    __shared__ float lred[8][16];

    const int t    = threadIdx.x;
    const int w    = t >> 6;
    const int lane = t & 63;
    const int quad = lane >> 4;
    const int lx   = lane & 15;
    const int par  = w >> 2;
    const int wg   = w & 3;
    const int qi   = blockIdx.x & 127;
    const int b    = blockIdx.x >> 7;
    const int qt   = (qi & 1) ? (127 - (qi >> 1)) : (qi >> 1);
    const int q0   = qt * 16;
    const int tb   = b * 128;

    half8 qa[4];
#pragma unroll
    for (int hc = 0; hc < 4; ++hc)
        qa[hc] = *(const half8*)&Qf[(((size_t)(tb + qt)) * 4 + hc) * 512 + lane * 8];

    f32x4 O[8];
#pragma unroll
    for (int hb = 0; hb < 8; ++hb) O[hb] = f32x4{0.f, 0.f, 0.f, 0.f};
    float lp[4] = {0.f, 0.f, 0.f, 0.f};

    const int nch = (qt >> 3) + 1;

    half8 kb[8];
    if (par < nch) {
        const f16* kp = &Kf[((size_t)(tb + par * 8 + wg * 2)) * 4 * 512 + lane * 8];
#pragma unroll
        for (int i = 0; i < 8; ++i) kb[i] = *(const half8*)&kp[(size_t)i * 512];
    }

    for (int c = par; c < nch; c += 2) {
        f32x4 Sc[2];
        Sc[0] = f32x4{0.f, 0.f, 0.f, 0.f};
        Sc[1] = f32x4{0.f, 0.f, 0.f, 0.f};
        __builtin_amdgcn_s_setprio(1);
#pragma unroll
        for (int sbl = 0; sbl < 2; ++sbl)
#pragma unroll
            for (int hc = 0; hc < 4; ++hc)
                Sc[sbl] = __builtin_amdgcn_mfma_f32_16x16x32_f16(
                    qa[hc], kb[sbl * 4 + hc], Sc[sbl], 0, 0, 0);
        __builtin_amdgcn_s_setprio(0);

        // prefetch next chunk's K into the SAME registers (no extra pressure;
        // latency hidden under exp + PV below)
        {
            const int cn = (c + 2 < nch) ? (c + 2) : c;
            const f16* kp = &Kf[((size_t)(tb + cn * 8 + wg * 2)) * 4 * 512 + lane * 8];
#pragma unroll
            for (int i = 0; i < 8; ++i) kb[i] = *(const half8*)&kp[(size_t)i * 512];
        }

        // V, first half (late + split: keeps peak VGPR pressure under 128)
        const f16* vp = &Vf[((size_t)(c * 4 + wg)) * 8 * 512 + lane * 8];
        half8 vb[4];
#pragma unroll
        for (int i = 0; i < 4; ++i) vb[i] = *(const half8*)&vp[(size_t)i * 512];

        const int s0 = c * 128 + wg * 32;
#pragma unroll
        for (int sbl = 0; sbl < 2; ++sbl) {
            const int sg  = s0 + sbl * 16 + lx;
            const int qp2 = sbl * 2 + (lx >> 3);
#pragma unroll
            for (int reg = 0; reg < 4; ++reg) {
                const int q = quad * 4 + reg;
                float p = (sg <= q0 + q)
                          ? __expf(Sc[sbl][reg] * 0.08838834764831845f - 10.0f)
                          : 0.f;
                lp[reg] += p;
                PL[w * 512 + (qp2 * 16 + q) * 8 + (lx & 7)] = (f16)p;
            }
        }

        const half8 pa = *(const half8*)&PL[w * 512 + lane * 8];

        __builtin_amdgcn_s_setprio(1);
#pragma unroll
        for (int hb = 0; hb < 4; ++hb)
            O[hb] = __builtin_amdgcn_mfma_f32_16x16x32_f16(pa, vb[hb], O[hb], 0, 0, 0);
        __builtin_amdgcn_s_setprio(0);
#pragma unroll
        for (int i = 0; i < 4; ++i) vb[i] = *(const half8*)&vp[(size_t)(4 + i) * 512];
        __builtin_amdgcn_s_setprio(1);
#pragma unroll
        for (int hb = 0; hb < 4; ++hb)
            O[4 + hb] = __builtin_amdgcn_mfma_f32_16x16x32_f16(pa, vb[hb], O[4 + hb], 0, 0, 0);
        __builtin_amdgcn_s_setprio(0);
    }

#pragma unroll
    for (int reg = 0; reg < 4; ++reg) {
        float v = lp[reg];
        v += __shfl_xor(v, 1, 64); v += __shfl_xor(v, 2, 64);
        v += __shfl_xor(v, 4, 64); v += __shfl_xor(v, 8, 64);
        if (lx == 0) lred[w][quad * 4 + reg] = v;
    }

    // ---- 3-barrier tree O-combine: 8 waves -> wave 0 ----
    if (w >= 4) {
#pragma unroll
        for (int hb = 0; hb < 8; ++hb)
#pragma unroll
            for (int reg = 0; reg < 4; ++reg)
                Obuf[w - 4][quad * 4 + reg][hb * 16 + lx] = O[hb][reg];
    }
    __syncthreads();
    if (w < 4) {
#pragma unroll
        for (int hb = 0; hb < 8; ++hb)
#pragma unroll
            for (int reg = 0; reg < 4; ++reg)
                O[hb][reg] += Obuf[w][quad * 4 + reg][hb * 16 + lx];
    }
    if (w == 2 || w == 3) {
#pragma unroll
        for (int hb = 0; hb < 8; ++hb)
#pragma unroll
            for (int reg = 0; reg < 4; ++reg)
                Obuf[w][quad * 4 + reg][hb * 16 + lx] = O[hb][reg];
    }
    __syncthreads();
    if (w < 2) {
#pragma unroll
        for (int hb = 0; hb < 8; ++hb)
#pragma unroll
            for (int reg = 0; reg < 4; ++reg)
                O[hb][reg] += Obuf[w + 2][quad * 4 + reg][hb * 16 + lx];
    }
    if (w == 1) {
#pragma unroll
        for (int hb = 0; hb < 8; ++hb)
#pragma unroll
            for (int reg = 0; reg < 4; ++reg)
                Obuf[1][quad * 4 + reg][hb * 16 + lx] = O[hb][reg];
    }
    __syncthreads();
    if (w == 0) {
        float linv[4];
#pragma unroll
        for (int reg = 0; reg < 4; ++reg) {
            float l = 0.f;
#pragma unroll
            for (int ww = 0; ww < 8; ++ww) l += lred[ww][quad * 4 + reg];
            linv[reg] = 1.0f / l;
        }
#pragma unroll
        for (int hb = 0; hb < 8; ++hb)
#pragma unroll
            for (int reg = 0; reg < 4; ++reg) {
                const float val =
                    (O[hb][reg] + Obuf[1][quad * 4 + reg][hb * 16 + lx]) * linv[reg];
                out[((size_t)(tb + qt) * 16 + quad * 4 + reg) * 128 + hb * 16 + lx] = val;
            }
    }
}

extern "C" void kernel_launch(void* const* d_in, const int* in_sizes, int n_in,
                              void* d_out, int out_size, void* d_ws, size_t ws_size,
                              hipStream_t stream) {
    const float4* X  = (const float4*)d_in[0];
    const float*  WQ = (const float*)d_in[1];
    const float*  WK = (const float*)d_in[2];
    const float*  WV = (const float*)d_in[3];

    f16* Wf = (f16*)d_ws;                     // 1024 frags  1 MB
    f16* Vf = Wf + (size_t)1024 * 512;        //  512 frags  0.5 MB
    f16* Qf = Vf + (size_t)512 * 512;         // 2048 frags  2 MB
    f16* Kf = Qf + (size_t)2048 * 512;        // 2048 frags  2 MB

    cvt_w_kernel<<<dim3(16, 8, 3), 256, 0, stream>>>(WQ, WK, WV, Wf, Vf);
    proj_kernel<<<256, 1024, 0, stream>>>(X, Wf, Qf, Kf);
    attn_kernel<<<512, 512, 0, stream>>>(Qf, Kf, Vf, (float*)d_out);
}

// Round 3
// 138.136 us; speedup vs baseline: 1.0401x; 1.0401x over previous
//
#include <hip/hip_runtime.h>
#include <stdint.h>

#define B 4
#define S 2048
#define E 2048
#define H 128

typedef _Float16 f16;
typedef _Float16 half4 __attribute__((ext_vector_type(4)));
typedef _Float16 half8 __attribute__((ext_vector_type(8)));
typedef float f32x4 __attribute__((ext_vector_type(4)));

// MFMA 16x16x32 f16 (m89/m91):
//   A-frag: lane(quad,lx) holds A[m=lx][k=quad*8+j]
//   B-frag: lane(quad,lx) holds B[k=quad*8+j][n=lx]
//   C/D  : lane(quad,lx) holds D[row=quad*4+reg][col=lx]
// FRAG-LINEAR GLOBAL: frag f = 512 f16 at dst[f*512 + lane*8 .. +8]:
// every frag load/store is one coalesced 1 KB b128 per wave.

// ---------------------------------------------------------------------------
// Kernel 0: W matrices fp32 [128][2048] -> frag-linear f16.  (unchanged)
// ---------------------------------------------------------------------------
__global__ __launch_bounds__(256) void cvt_w_kernel(
    const float* __restrict__ WQ, const float* __restrict__ WK,
    const float* __restrict__ WV,
    f16* __restrict__ Wf, f16* __restrict__ Vf)
{
    __shared__ __align__(16) f16 LT[4 * 512];
    const int t   = threadIdx.x;
    const int cc  = blockIdx.x;
    const int rt  = blockIdx.y;
    const int mat = blockIdx.z;
    const float* src = (mat == 0) ? WQ : (mat == 1) ? WK : WV;

#pragma unroll
    for (int i = 0; i < 2; ++i) {
        const int idx = i * 256 + t;
        const int row = idx >> 5;
        const int c4  = idx & 31;
        float4 v = ((const float4*)src)[(size_t)(rt * 16 + row) * (E / 4) + cc * 32 + c4];
        const int e0   = c4 * 4;
        const int kcl  = e0 >> 5;
        const int quad = (e0 >> 3) & 3;
        const int j    = e0 & 7;
        half4 hv;
        hv[0] = (f16)v.x; hv[1] = (f16)v.y; hv[2] = (f16)v.z; hv[3] = (f16)v.w;
        *(half4*)&LT[(kcl * 64 + quad * 16 + row) * 8 + j] = hv;
    }
    __syncthreads();

    const half8 val = *(const half8*)&LT[t * 8];
    const int kcg = cc * 4 + (t >> 6);
    const int ln  = t & 63;
    if (mat == 2) *(half8*)&Vf[((size_t)kcg * 8  + rt)           * 512 + ln * 8] = val;
    else          *(half8*)&Wf[((size_t)kcg * 16 + rt + mat * 8) * 512 + ln * 8] = val;
}

// ---------------------------------------------------------------------------
// Kernel 1 (v4): Q,K projection. 256 blocks x 1024 thr, 32 rows/block.
// 8 K-groups of 8 kc; 2 x 16 KB LDS double buffer; loads issued 2 groups
// ahead into named register sets (xA/xB). ONE raw s_barrier per group with
// manual lgkmcnt(0) only -- prefetch global loads are NOT drained at the
// barrier (T3/T4: counted vmcnt stays in flight; compiler emits the exact
// data-dep vmcnt for xA/xB use).
//   iter g: [load(g+2)] compute(g, buf[g&1]) ; write(g+1 -> buf[(g+1)&1]) ;
//           s_waitcnt lgkmcnt(0) ; s_barrier
// Safety: write(g+1) touches the opposite buffer of compute(g); last reader
// of buf[(g+1)&1] was compute(g-1), sealed by the barrier ending iter g-1.
// ---------------------------------------------------------------------------
__global__ __launch_bounds__(1024, 4) void proj_kernel(
    const float4* __restrict__ X,      // [B*S][E/4] fp32
    const f16* __restrict__ Wf,
    f16* __restrict__ Qf, f16* __restrict__ Kf)
{
    __shared__ __align__(16) f16 XA[2 * 1024 * 8];   // 2 x 16 KB
    const int t    = threadIdx.x;
    const int w    = t >> 6;
    const int lane = t & 63;
    const int quad = lane >> 4;
    const int lx   = lane & 15;
    const int r0   = blockIdx.x * 32;
    const int rot  = blockIdx.x & 7;

    // per-thread staging geometry: 1 half8 slot per group
    const int srow = t >> 5;         // 0..31
    const int cp   = t & 31;         // 0..31  (2 consecutive float4)
    const int skcl = cp >> 2;        // 0..7
    const int sqs  = cp & 3;
    const int srt  = srow >> 4;
    const int sm   = srow & 15;
    const int smp  = sm ^ ((sqs << 1) | (skcl & 1));          // bank swizzle
    const size_t ldst = (size_t)(skcl * 128 + srt * 64 + sqs * 16 + smp) * 8;
    const float4* xrow = &X[(size_t)(r0 + srow) * (E / 4) + cp * 2];

    float4 xA0, xA1, xB0, xB1;

    f32x4 C0 = f32x4{0.f, 0.f, 0.f, 0.f};
    f32x4 C1 = f32x4{0.f, 0.f, 0.f, 0.f};
    const f16* wbase = &Wf[(size_t)w * 512 + lane * 8];       // frag kc*16 + w

    auto cvt_write = [&](int g, float4 v0, float4 v1) {
        f16* buf = &XA[(size_t)(g & 1) * 1024 * 8];
        half8 hv;
        hv[0] = (f16)v0.x; hv[1] = (f16)v0.y; hv[2] = (f16)v0.z; hv[3] = (f16)v0.w;
        hv[4] = (f16)v1.x; hv[5] = (f16)v1.y; hv[6] = (f16)v1.z; hv[7] = (f16)v1.w;
        *(half8*)&buf[ldst] = hv;
    };
    auto compute = [&](int g) {
        const f16* buf = &XA[(size_t)(g & 1) * 1024 * 8];
#pragma unroll
        for (int k = 0; k < 8; ++k) {
            const int k2  = (k + rot) & 7;
            const int kc  = g * 8 + k2;
            const int lxs = lx ^ ((quad << 1) | (k2 & 1));
            half8 b  = *(const half8*)&wbase[(size_t)kc * 16 * 512];          // L2
            half8 a0 = *(const half8*)&buf[(size_t)(k2 * 128      + quad * 16 + lxs) * 8];
            half8 a1 = *(const half8*)&buf[(size_t)(k2 * 128 + 64 + quad * 16 + lxs) * 8];
            C0 = __builtin_amdgcn_mfma_f32_16x16x32_f16(a0, b, C0, 0, 0, 0);
            C1 = __builtin_amdgcn_mfma_f32_16x16x32_f16(a1, b, C1, 0, 0, 0);
        }
    };

    // prologue: fill both register sets, write group 0, seal buffer 0
    { const float4* p = xrow;        xA0 = p[0]; xA1 = p[1]; }   // g=0
    { const float4* p = xrow + 64;   xB0 = p[0]; xB1 = p[1]; }   // g=1
    cvt_write(0, xA0, xA1);
    asm volatile("s_waitcnt lgkmcnt(0)" ::: "memory");
    __builtin_amdgcn_s_barrier();

    for (int gg = 0; gg < 4; ++gg) {
        const int g0 = gg * 2;                       // even group: set A frees
        if (g0 + 2 < 8) { const float4* p = xrow + (g0 + 2) * 64; xA0 = p[0]; xA1 = p[1]; }
        compute(g0);
        cvt_write(g0 + 1, xB0, xB1);
        asm volatile("s_waitcnt lgkmcnt(0)" ::: "memory");
        __builtin_amdgcn_s_barrier();

        const int g1 = g0 + 1;                       // odd group: set B frees
        if (g1 + 2 < 8) { const float4* p = xrow + (g1 + 2) * 64; xB0 = p[0]; xB1 = p[1]; }
        compute(g1);
        if (g1 < 7) {
            cvt_write(g1 + 1, xA0, xA1);
            asm volatile("s_waitcnt lgkmcnt(0)" ::: "memory");
            __builtin_amdgcn_s_barrier();
        }
    }

    // ---- epilogue: C -> LT (target frag layout, reuse buf0) -> global ----
    // compute(7) read buf1; LT = buf0 whose last readers (compute(6)) were
    // sealed by the final barrier above -> safe to overwrite.
    f16* LT = XA;                         // 16 frags = 16 KB
    {
        const int qt2 = (w & 1) * 2 + (lx >> 3);
        const int jt  = lx & 7;
        const int fl  = w >> 1;           // 0..7: (mat,hc)
#pragma unroll
        for (int reg = 0; reg < 4; ++reg) {
            LT[(size_t)((fl       * 64) + qt2 * 16 + quad * 4 + reg) * 8 + jt] = (f16)C0[reg];
            LT[(size_t)(((fl + 8) * 64) + qt2 * 16 + quad * 4 + reg) * 8 + jt] = (f16)C1[reg];
        }
    }
    __syncthreads();
    {
        const int f  = t >> 6;            // 0..15
        const int ln = t & 63;
        const half8 v = *(const half8*)&LT[(size_t)f * 512 + ln * 8];
        const int rt  = f >> 3;
        const int hc  = f & 3;
        const int mat = (f >> 2) & 1;
        f16* dst = mat ? Kf : Qf;
        *(half8*)&dst[((size_t)(blockIdx.x * 2 + rt) * 4 + hc) * 512 + ln * 8] = v;
    }
}

// ---------------------------------------------------------------------------
// Kernel 2: attention (reverted to known-good v1). 512 blocks x 512 thr.
// Wave = (parity, k-slice); fixed-max softmax -> order-free chunk sums;
// barrier-free k-loop; 8-step O/l combine epilogue.
// ---------------------------------------------------------------------------
__global__ __launch_bounds__(512, 4) void attn_kernel(
    const f16* __restrict__ Qf, const f16* __restrict__ Kf,
    const f16* __restrict__ Vf,
    float* __restrict__ out)
{
    __shared__ __align__(16) f16 PL[8 * 512];
    __shared__ float Obuf[16][132];
    __shared__ float lred[8][16];

    const int t    = threadIdx.x;
    const int w    = t >> 6;
    const int lane = t & 63;
    const int quad = lane >> 4;
    const int lx   = lane & 15;
    const int par  = w >> 2;
    const int wg   = w & 3;
    const int qi   = blockIdx.x & 127;
    const int b    = blockIdx.x >> 7;
    const int qt   = (qi & 1) ? (127 - (qi >> 1)) : (qi >> 1);
    const int q0   = qt * 16;
    const int tb   = b * 128;

    half8 qa[4];
#pragma unroll
    for (int hc = 0; hc < 4; ++hc)
        qa[hc] = *(const half8*)&Qf[(((size_t)(tb + qt)) * 4 + hc) * 512 + lane * 8];

    f32x4 O[8];
#pragma unroll
    for (int hb = 0; hb < 8; ++hb) O[hb] = f32x4{0.f, 0.f, 0.f, 0.f};
    float lp[4] = {0.f, 0.f, 0.f, 0.f};

    const int nch = (qt >> 3) + 1;
    for (int c = par; c < nch; c += 2) {
        half8 kb[8], vb[8];
        const f16* kp = &Kf[((size_t)(tb + c * 8 + wg * 2)) * 4 * 512 + lane * 8];
#pragma unroll
        for (int i = 0; i < 8; ++i) kb[i] = *(const half8*)&kp[(size_t)i * 512];
        const f16* vp = &Vf[((size_t)(c * 4 + wg)) * 8 * 512 + lane * 8];
#pragma unroll
        for (int i = 0; i < 8; ++i) vb[i] = *(const half8*)&vp[(size_t)i * 512];

        f32x4 Sc[2];
        Sc[0] = f32x4{0.f, 0.f, 0.f, 0.f};
        Sc[1] = f32x4{0.f, 0.f, 0.f, 0.f};
#pragma unroll
        for (int sbl = 0; sbl < 2; ++sbl)
#pragma unroll
            for (int hc = 0; hc < 4; ++hc)
                Sc[sbl] = __builtin_amdgcn_mfma_f32_16x16x32_f16(
                    qa[hc], kb[sbl * 4 + hc], Sc[sbl], 0, 0, 0);

        const int s0 = c * 128 + wg * 32;
#pragma unroll
        for (int sbl = 0; sbl < 2; ++sbl) {
            const int sg  = s0 + sbl * 16 + lx;
            const int qp2 = sbl * 2 + (lx >> 3);
#pragma unroll
            for (int reg = 0; reg < 4; ++reg) {
                const int q = quad * 4 + reg;
                float p = (sg <= q0 + q)
                          ? __expf(Sc[sbl][reg] * 0.08838834764831845f - 10.0f)
                          : 0.f;
                lp[reg] += p;
                PL[w * 512 + (qp2 * 16 + q) * 8 + (lx & 7)] = (f16)p;
            }
        }

        const half8 pa = *(const half8*)&PL[w * 512 + lane * 8];
#pragma unroll
        for (int hb = 0; hb < 8; ++hb)
            O[hb] = __builtin_amdgcn_mfma_f32_16x16x32_f16(pa, vb[hb], O[hb], 0, 0, 0);
    }

#pragma unroll
    for (int reg = 0; reg < 4; ++reg) {
        float v = lp[reg];
        v += __shfl_xor(v, 1, 64); v += __shfl_xor(v, 2, 64);
        v += __shfl_xor(v, 4, 64); v += __shfl_xor(v, 8, 64);
        if (lx == 0) lred[w][quad * 4 + reg] = v;
    }

    if (w == 0) {
#pragma unroll
        for (int hb = 0; hb < 8; ++hb)
#pragma unroll
            for (int reg = 0; reg < 4; ++reg)
                Obuf[quad * 4 + reg][hb * 16 + lx] = O[hb][reg];
    }
    __syncthreads();
    for (int ww = 1; ww < 8; ++ww) {
        if (w == ww) {
#pragma unroll
            for (int hb = 0; hb < 8; ++hb)
#pragma unroll
                for (int reg = 0; reg < 4; ++reg)
                    Obuf[quad * 4 + reg][hb * 16 + lx] += O[hb][reg];
        }
        __syncthreads();
    }

    {
        const int h = t & 127, qg = t >> 7;
#pragma unroll
        for (int i = 0; i < 4; ++i) {
            const int qrow = qg * 4 + i;
            float l = 0.f;
#pragma unroll
            for (int ww = 0; ww < 8; ++ww) l += lred[ww][qrow];
            out[((size_t)(tb + qt) * 16 + qrow) * 128 + h] = Obuf[qrow][h] / l;
        }
    }
}

extern "C" void kernel_launch(void* const* d_in, const int* in_sizes, int n_in,
                              void* d_out, int out_size, void* d_ws, size_t ws_size,
                              hipStream_t stream) {
    const float4* X  = (const float4*)d_in[0];
    const float*  WQ = (const float*)d_in[1];
    const float*  WK = (const float*)d_in[2];
    const float*  WV = (const float*)d_in[3];

    f16* Wf = (f16*)d_ws;                     // 1024 frags  1 MB
    f16* Vf = Wf + (size_t)1024 * 512;        //  512 frags  0.5 MB
    f16* Qf = Vf + (size_t)512 * 512;         // 2048 frags  2 MB
    f16* Kf = Qf + (size_t)2048 * 512;        // 2048 frags  2 MB

    cvt_w_kernel<<<dim3(16, 8, 3), 256, 0, stream>>>(WQ, WK, WV, Wf, Vf);
    proj_kernel<<<256, 1024, 0, stream>>>(X, Wf, Qf, Kf);
    attn_kernel<<<512, 512, 0, stream>>>(Qf, Kf, Vf, (float*)d_out);
}

// Round 4
// 127.100 us; speedup vs baseline: 1.1305x; 1.0868x over previous
//
#include <hip/hip_runtime.h>
#include <stdint.h>

#define B 4
#define S 2048
#define E 2048
#define H 128

typedef _Float16 f16;
typedef _Float16 half4 __attribute__((ext_vector_type(4)));
typedef _Float16 half8 __attribute__((ext_vector_type(8)));
typedef float f32x4 __attribute__((ext_vector_type(4)));

// MFMA 16x16x32 f16 (m89/m91):
//   A-frag: lane(quad,lx) holds A[m=lx][k=quad*8+j]
//   B-frag: lane(quad,lx) holds B[k=quad*8+j][n=lx]
//   C/D  : lane(quad,lx) holds D[row=quad*4+reg][col=lx]
// FRAG-LINEAR GLOBAL: frag f = 512 f16 at dst[f*512 + lane*8 .. +8]:
// every frag load/store is one coalesced 1 KB b128 per wave.

// ---------------------------------------------------------------------------
// Kernel 0: W matrices fp32 [128][2048] -> frag-linear f16.  (unchanged)
// ---------------------------------------------------------------------------
__global__ __launch_bounds__(256) void cvt_w_kernel(
    const float* __restrict__ WQ, const float* __restrict__ WK,
    const float* __restrict__ WV,
    f16* __restrict__ Wf, f16* __restrict__ Vf)
{
    __shared__ __align__(16) f16 LT[4 * 512];
    const int t   = threadIdx.x;
    const int cc  = blockIdx.x;
    const int rt  = blockIdx.y;
    const int mat = blockIdx.z;
    const float* src = (mat == 0) ? WQ : (mat == 1) ? WK : WV;

#pragma unroll
    for (int i = 0; i < 2; ++i) {
        const int idx = i * 256 + t;
        const int row = idx >> 5;
        const int c4  = idx & 31;
        float4 v = ((const float4*)src)[(size_t)(rt * 16 + row) * (E / 4) + cc * 32 + c4];
        const int e0   = c4 * 4;
        const int kcl  = e0 >> 5;
        const int quad = (e0 >> 3) & 3;
        const int j    = e0 & 7;
        half4 hv;
        hv[0] = (f16)v.x; hv[1] = (f16)v.y; hv[2] = (f16)v.z; hv[3] = (f16)v.w;
        *(half4*)&LT[(kcl * 64 + quad * 16 + row) * 8 + j] = hv;
    }
    __syncthreads();

    const half8 val = *(const half8*)&LT[t * 8];
    const int kcg = cc * 4 + (t >> 6);
    const int ln  = t & 63;
    if (mat == 2) *(half8*)&Vf[((size_t)kcg * 8  + rt)           * 512 + ln * 8] = val;
    else          *(half8*)&Wf[((size_t)kcg * 16 + rt + mat * 8) * 512 + ln * 8] = val;
}

// ---------------------------------------------------------------------------
// Kernel 1 (v2, known-good from R1): Q,K projection. 256 blocks x 1024 thr,
// 32 rows/block, full-K X staged in 128 KB LDS (1 block/CU, 4 waves/SIMD).
// Coalesced staging + bank swizzle; barrier-free 64-iter K-loop; per-block
// kc rotation de-phases the Wf L2 walk.
// ---------------------------------------------------------------------------
__global__ __launch_bounds__(1024, 4) void proj_kernel(
    const float4* __restrict__ X,      // [B*S][E/4] fp32
    const f16* __restrict__ Wf,
    f16* __restrict__ Qf, f16* __restrict__ Kf)
{
    __shared__ __align__(16) f16 XA[8192 * 8];   // 128 KB; slot = 16B unit
    const int t    = threadIdx.x;
    const int w    = t >> 6;
    const int lane = t & 63;
    const int quad = lane >> 4;
    const int lx   = lane & 15;
    const int r0   = blockIdx.x * 32;

    // ---- stage X: 32 rows x 2048 k, fp32 -> f16 frag-linear, coalesced ----
    float4 xv[16];
#pragma unroll
    for (int i = 0; i < 8; ++i) {
        const int p   = i * 1024 + t;
        const int row = p >> 8;
        const int c42 = p & 255;
        const float4* xp = &X[(size_t)(r0 + row) * (E / 4) + c42 * 2];
        xv[i * 2]     = xp[0];
        xv[i * 2 + 1] = xp[1];
    }
#pragma unroll
    for (int i = 0; i < 8; ++i) {
        const int p   = i * 1024 + t;
        const int row = p >> 8;
        const int c42 = p & 255;
        const int kc  = c42 >> 2;
        const int qs  = c42 & 3;
        const int rt  = row >> 4;
        const int m   = row & 15;
        const int mp  = m ^ ((qs << 1) | (kc & 1));      // bank swizzle
        half8 hv;
        hv[0] = (f16)xv[i * 2].x;     hv[1] = (f16)xv[i * 2].y;
        hv[2] = (f16)xv[i * 2].z;     hv[3] = (f16)xv[i * 2].w;
        hv[4] = (f16)xv[i * 2 + 1].x; hv[5] = (f16)xv[i * 2 + 1].y;
        hv[6] = (f16)xv[i * 2 + 1].z; hv[7] = (f16)xv[i * 2 + 1].w;
        *(half8*)&XA[(size_t)(kc * 128 + rt * 64 + qs * 16 + mp) * 8] = hv;
    }
    __syncthreads();

    // ---- barrier-free K-loop: 64 x (2 ds_read + 1 global b128 + 2 MFMA) ----
    f32x4 C0 = f32x4{0.f, 0.f, 0.f, 0.f};
    f32x4 C1 = f32x4{0.f, 0.f, 0.f, 0.f};
    const f16* wbase = &Wf[(size_t)w * 512 + lane * 8];     // frag kc*16 + w
    const int rot = blockIdx.x & 63;
#pragma unroll 8
    for (int kk = 0; kk < 64; ++kk) {
        const int kc  = (kk + rot) & 63;
        const int lxs = lx ^ ((quad << 1) | (kc & 1));
        half8 b  = *(const half8*)&wbase[(size_t)kc * 16 * 512];          // L2
        half8 a0 = *(const half8*)&XA[(size_t)(kc * 128      + quad * 16 + lxs) * 8];
        half8 a1 = *(const half8*)&XA[(size_t)(kc * 128 + 64 + quad * 16 + lxs) * 8];
        C0 = __builtin_amdgcn_mfma_f32_16x16x32_f16(a0, b, C0, 0, 0, 0);
        C1 = __builtin_amdgcn_mfma_f32_16x16x32_f16(a1, b, C1, 0, 0, 0);
    }

    // ---- epilogue: C -> LT (target frag layout, reuse XA) -> global ----
    __syncthreads();                      // all XA reads done; alias as LT
    f16* LT = XA;                         // 16 frags = 16 KB
    {
        const int qt2 = (w & 1) * 2 + (lx >> 3);
        const int jt  = lx & 7;
        const int fl  = w >> 1;           // 0..7: (mat,hc)
#pragma unroll
        for (int reg = 0; reg < 4; ++reg) {
            LT[(size_t)((fl      * 64) + qt2 * 16 + quad * 4 + reg) * 8 + jt] = (f16)C0[reg];
            LT[(size_t)(((fl + 8) * 64) + qt2 * 16 + quad * 4 + reg) * 8 + jt] = (f16)C1[reg];
        }
    }
    __syncthreads();
    {
        const int f  = t >> 6;            // 0..15
        const int ln = t & 63;
        const half8 v = *(const half8*)&LT[(size_t)f * 512 + ln * 8];
        const int rt  = f >> 3;
        const int hc  = f & 3;
        const int mat = (f >> 2) & 1;
        f16* dst = mat ? Kf : Qf;
        *(half8*)&dst[((size_t)(blockIdx.x * 2 + rt) * 4 + hc) * 512 + ln * 8] = v;
    }
}

// ---------------------------------------------------------------------------
// Kernel 2: attention v1 + ONE change: CU-load-balanced (b,qt) remap.
// Grid = 512 = exactly 2 blocks/CU, all co-resident. CP round-robins XCDs,
// so blocks i and i+256 share a CU. Old map gave them the SAME qt (1..17
// chunk workload) -> worst CU did 34 chunk-units vs balanced 17. New map:
// adjacent blocks sum to 127 (old interleave kept) AND (i, i+256) sum to
// 127 (round 1 takes the complement) -> balanced under either pairing.
// Everything else identical to v1.
// ---------------------------------------------------------------------------
__global__ __launch_bounds__(512, 4) void attn_kernel(
    const f16* __restrict__ Qf, const f16* __restrict__ Kf,
    const f16* __restrict__ Vf,
    float* __restrict__ out)
{
    __shared__ __align__(16) f16 PL[8 * 512];
    __shared__ float Obuf[16][132];
    __shared__ float lred[8][16];

    const int t    = threadIdx.x;
    const int w    = t >> 6;
    const int lane = t & 63;
    const int quad = lane >> 4;
    const int lx   = lane & 15;
    const int par  = w >> 2;
    const int wg   = w & 3;

    const int j    = blockIdx.x & 255;
    const int r    = blockIdx.x >> 8;      // co-resident round on each CU
    const int u    = j & 127;
    const int q0t  = (u & 1) ? (127 - (u >> 1)) : (u >> 1);
    const int qt   = r ? (127 - q0t) : q0t; // CU's two blocks: qt + qt' = 127
    const int b    = (j >> 7) + (r << 1);

    const int q0   = qt * 16;
    const int tb   = b * 128;

    half8 qa[4];
#pragma unroll
    for (int hc = 0; hc < 4; ++hc)
        qa[hc] = *(const half8*)&Qf[(((size_t)(tb + qt)) * 4 + hc) * 512 + lane * 8];

    f32x4 O[8];
#pragma unroll
    for (int hb = 0; hb < 8; ++hb) O[hb] = f32x4{0.f, 0.f, 0.f, 0.f};
    float lp[4] = {0.f, 0.f, 0.f, 0.f};

    const int nch = (qt >> 3) + 1;
    for (int c = par; c < nch; c += 2) {
        half8 kb[8], vb[8];
        const f16* kp = &Kf[((size_t)(tb + c * 8 + wg * 2)) * 4 * 512 + lane * 8];
#pragma unroll
        for (int i = 0; i < 8; ++i) kb[i] = *(const half8*)&kp[(size_t)i * 512];
        const f16* vp = &Vf[((size_t)(c * 4 + wg)) * 8 * 512 + lane * 8];
#pragma unroll
        for (int i = 0; i < 8; ++i) vb[i] = *(const half8*)&vp[(size_t)i * 512];

        f32x4 Sc[2];
        Sc[0] = f32x4{0.f, 0.f, 0.f, 0.f};
        Sc[1] = f32x4{0.f, 0.f, 0.f, 0.f};
#pragma unroll
        for (int sbl = 0; sbl < 2; ++sbl)
#pragma unroll
            for (int hc = 0; hc < 4; ++hc)
                Sc[sbl] = __builtin_amdgcn_mfma_f32_16x16x32_f16(
                    qa[hc], kb[sbl * 4 + hc], Sc[sbl], 0, 0, 0);

        const int s0 = c * 128 + wg * 32;
#pragma unroll
        for (int sbl = 0; sbl < 2; ++sbl) {
            const int sg  = s0 + sbl * 16 + lx;
            const int qp2 = sbl * 2 + (lx >> 3);
#pragma unroll
            for (int reg = 0; reg < 4; ++reg) {
                const int q = quad * 4 + reg;
                float p = (sg <= q0 + q)
                          ? __expf(Sc[sbl][reg] * 0.08838834764831845f - 10.0f)
                          : 0.f;
                lp[reg] += p;
                PL[w * 512 + (qp2 * 16 + q) * 8 + (lx & 7)] = (f16)p;
            }
        }

        const half8 pa = *(const half8*)&PL[w * 512 + lane * 8];
#pragma unroll
        for (int hb = 0; hb < 8; ++hb)
            O[hb] = __builtin_amdgcn_mfma_f32_16x16x32_f16(pa, vb[hb], O[hb], 0, 0, 0);
    }

#pragma unroll
    for (int reg = 0; reg < 4; ++reg) {
        float v = lp[reg];
        v += __shfl_xor(v, 1, 64); v += __shfl_xor(v, 2, 64);
        v += __shfl_xor(v, 4, 64); v += __shfl_xor(v, 8, 64);
        if (lx == 0) lred[w][quad * 4 + reg] = v;
    }

    if (w == 0) {
#pragma unroll
        for (int hb = 0; hb < 8; ++hb)
#pragma unroll
            for (int reg = 0; reg < 4; ++reg)
                Obuf[quad * 4 + reg][hb * 16 + lx] = O[hb][reg];
    }
    __syncthreads();
    for (int ww = 1; ww < 8; ++ww) {
        if (w == ww) {
#pragma unroll
            for (int hb = 0; hb < 8; ++hb)
#pragma unroll
                for (int reg = 0; reg < 4; ++reg)
                    Obuf[quad * 4 + reg][hb * 16 + lx] += O[hb][reg];
        }
        __syncthreads();
    }

    {
        const int h = t & 127, qg = t >> 7;
#pragma unroll
        for (int i = 0; i < 4; ++i) {
            const int qrow = qg * 4 + i;
            float l = 0.f;
#pragma unroll
            for (int ww = 0; ww < 8; ++ww) l += lred[ww][qrow];
            out[((size_t)(tb + qt) * 16 + qrow) * 128 + h] = Obuf[qrow][h] / l;
        }
    }
}

extern "C" void kernel_launch(void* const* d_in, const int* in_sizes, int n_in,
                              void* d_out, int out_size, void* d_ws, size_t ws_size,
                              hipStream_t stream) {
    const float4* X  = (const float4*)d_in[0];
    const float*  WQ = (const float*)d_in[1];
    const float*  WK = (const float*)d_in[2];
    const float*  WV = (const float*)d_in[3];

    f16* Wf = (f16*)d_ws;                     // 1024 frags  1 MB
    f16* Vf = Wf + (size_t)1024 * 512;        //  512 frags  0.5 MB
    f16* Qf = Vf + (size_t)512 * 512;         // 2048 frags  2 MB
    f16* Kf = Qf + (size_t)2048 * 512;        // 2048 frags  2 MB

    cvt_w_kernel<<<dim3(16, 8, 3), 256, 0, stream>>>(WQ, WK, WV, Wf, Vf);
    proj_kernel<<<256, 1024, 0, stream>>>(X, Wf, Qf, Kf);
    attn_kernel<<<512, 512, 0, stream>>>(Qf, Kf, Vf, (float*)d_out);
}

// Round 5
// 127.093 us; speedup vs baseline: 1.1305x; 1.0001x over previous
//
#include <hip/hip_runtime.h>
#include <stdint.h>

#define B 4
#define S 2048
#define E 2048
#define H 128

typedef _Float16 f16;
typedef _Float16 half4 __attribute__((ext_vector_type(4)));
typedef _Float16 half8 __attribute__((ext_vector_type(8)));
typedef float f32x4 __attribute__((ext_vector_type(4)));

// MFMA 16x16x32 f16 (m89/m91):
//   A-frag: lane(quad,lx) holds A[m=lx][k=quad*8+j]
//   B-frag: lane(quad,lx) holds B[k=quad*8+j][n=lx]
//   C/D  : lane(quad,lx) holds D[row=quad*4+reg][col=lx]
// FRAG-LINEAR GLOBAL: frag f = 512 f16 at dst[f*512 + lane*8 .. +8]:
// every frag load/store is one coalesced 1 KB b128 per wave.

// Raw barrier: lgkm-only wait (LDS visibility) + workgroup barrier.
// Global prefetch loads stay in flight across it (no vmcnt drain -- the
// __syncthreads trap). "memory" clobbers fence compiler motion both sides.
#define BAR() do { asm volatile("s_waitcnt lgkmcnt(0)" ::: "memory"); \
    __builtin_amdgcn_s_barrier(); \
    asm volatile("" ::: "memory"); } while (0)

// ---------------------------------------------------------------------------
// Kernel 0: W matrices fp32 [128][2048] -> frag-linear f16.  (unchanged)
// ---------------------------------------------------------------------------
__global__ __launch_bounds__(256) void cvt_w_kernel(
    const float* __restrict__ WQ, const float* __restrict__ WK,
    const float* __restrict__ WV,
    f16* __restrict__ Wf, f16* __restrict__ Vf)
{
    __shared__ __align__(16) f16 LT[4 * 512];
    const int t   = threadIdx.x;
    const int cc  = blockIdx.x;
    const int rt  = blockIdx.y;
    const int mat = blockIdx.z;
    const float* src = (mat == 0) ? WQ : (mat == 1) ? WK : WV;

#pragma unroll
    for (int i = 0; i < 2; ++i) {
        const int idx = i * 256 + t;
        const int row = idx >> 5;
        const int c4  = idx & 31;
        float4 v = ((const float4*)src)[(size_t)(rt * 16 + row) * (E / 4) + cc * 32 + c4];
        const int e0   = c4 * 4;
        const int kcl  = e0 >> 5;
        const int quad = (e0 >> 3) & 3;
        const int j    = e0 & 7;
        half4 hv;
        hv[0] = (f16)v.x; hv[1] = (f16)v.y; hv[2] = (f16)v.z; hv[3] = (f16)v.w;
        *(half4*)&LT[(kcl * 64 + quad * 16 + row) * 8 + j] = hv;
    }
    __syncthreads();

    const half8 val = *(const half8*)&LT[t * 8];
    const int kcg = cc * 4 + (t >> 6);
    const int ln  = t & 63;
    if (mat == 2) *(half8*)&Vf[((size_t)kcg * 8  + rt)           * 512 + ln * 8] = val;
    else          *(half8*)&Wf[((size_t)kcg * 16 + rt + mat * 8) * 512 + ln * 8] = val;
}

// ---------------------------------------------------------------------------
// Kernel 1 (v2, known-good): Q,K projection. 256 blocks x 1024 thr, 32 rows,
// full-K X staged in 128 KB LDS, barrier-free 64-iter K-loop. (unchanged)
// ---------------------------------------------------------------------------
__global__ __launch_bounds__(1024, 4) void proj_kernel(
    const float4* __restrict__ X,      // [B*S][E/4] fp32
    const f16* __restrict__ Wf,
    f16* __restrict__ Qf, f16* __restrict__ Kf)
{
    __shared__ __align__(16) f16 XA[8192 * 8];   // 128 KB; slot = 16B unit
    const int t    = threadIdx.x;
    const int w    = t >> 6;
    const int lane = t & 63;
    const int quad = lane >> 4;
    const int lx   = lane & 15;
    const int r0   = blockIdx.x * 32;

    float4 xv[16];
#pragma unroll
    for (int i = 0; i < 8; ++i) {
        const int p   = i * 1024 + t;
        const int row = p >> 8;
        const int c42 = p & 255;
        const float4* xp = &X[(size_t)(r0 + row) * (E / 4) + c42 * 2];
        xv[i * 2]     = xp[0];
        xv[i * 2 + 1] = xp[1];
    }
#pragma unroll
    for (int i = 0; i < 8; ++i) {
        const int p   = i * 1024 + t;
        const int row = p >> 8;
        const int c42 = p & 255;
        const int kc  = c42 >> 2;
        const int qs  = c42 & 3;
        const int rt  = row >> 4;
        const int m   = row & 15;
        const int mp  = m ^ ((qs << 1) | (kc & 1));      // bank swizzle
        half8 hv;
        hv[0] = (f16)xv[i * 2].x;     hv[1] = (f16)xv[i * 2].y;
        hv[2] = (f16)xv[i * 2].z;     hv[3] = (f16)xv[i * 2].w;
        hv[4] = (f16)xv[i * 2 + 1].x; hv[5] = (f16)xv[i * 2 + 1].y;
        hv[6] = (f16)xv[i * 2 + 1].z; hv[7] = (f16)xv[i * 2 + 1].w;
        *(half8*)&XA[(size_t)(kc * 128 + rt * 64 + qs * 16 + mp) * 8] = hv;
    }
    __syncthreads();

    f32x4 C0 = f32x4{0.f, 0.f, 0.f, 0.f};
    f32x4 C1 = f32x4{0.f, 0.f, 0.f, 0.f};
    const f16* wbase = &Wf[(size_t)w * 512 + lane * 8];     // frag kc*16 + w
    const int rot = blockIdx.x & 63;
#pragma unroll 8
    for (int kk = 0; kk < 64; ++kk) {
        const int kc  = (kk + rot) & 63;
        const int lxs = lx ^ ((quad << 1) | (kc & 1));
        half8 b  = *(const half8*)&wbase[(size_t)kc * 16 * 512];          // L2
        half8 a0 = *(const half8*)&XA[(size_t)(kc * 128      + quad * 16 + lxs) * 8];
        half8 a1 = *(const half8*)&XA[(size_t)(kc * 128 + 64 + quad * 16 + lxs) * 8];
        C0 = __builtin_amdgcn_mfma_f32_16x16x32_f16(a0, b, C0, 0, 0, 0);
        C1 = __builtin_amdgcn_mfma_f32_16x16x32_f16(a1, b, C1, 0, 0, 0);
    }

    __syncthreads();                      // all XA reads done; alias as LT
    f16* LT = XA;                         // 16 frags = 16 KB
    {
        const int qt2 = (w & 1) * 2 + (lx >> 3);
        const int jt  = lx & 7;
        const int fl  = w >> 1;           // 0..7: (mat,hc)
#pragma unroll
        for (int reg = 0; reg < 4; ++reg) {
            LT[(size_t)((fl      * 64) + qt2 * 16 + quad * 4 + reg) * 8 + jt] = (f16)C0[reg];
            LT[(size_t)(((fl + 8) * 64) + qt2 * 16 + quad * 4 + reg) * 8 + jt] = (f16)C1[reg];
        }
    }
    __syncthreads();
    {
        const int f  = t >> 6;            // 0..15
        const int ln = t & 63;
        const half8 v = *(const half8*)&LT[(size_t)f * 512 + ln * 8];
        const int rt  = f >> 3;
        const int hc  = f & 3;
        const int mat = (f >> 2) & 1;
        f16* dst = mat ? Kf : Qf;
        *(half8*)&dst[((size_t)(blockIdx.x * 2 + rt) * 4 + hc) * 512 + ln * 8] = v;
    }
}

// ---------------------------------------------------------------------------
// Kernel 2 (v3): attention, latency-pipelined wave re-split.
// 512 blocks x 512 thr (2/CU), R4 CU-balanced (b,qt) map kept verbatim.
// Wave w owns: QK k-tile w (16 k-cols) + PV h-tile w (16 h-cols).
// K frags (k-tile w x 4 hc) and V frags (4 kc x h-tile w) are DISJOINT per
// wave -> direct global loads, no duplication, and small enough (32 VGPR)
// to DOUBLE-BUFFER in registers: chunk c+1 loads issue before chunk c's
// compute, hidden under a full chunk. P crosses waves via 4 KB LDS with
// 2 raw barriers/chunk (lgkm-only: prefetch stays in flight).
// Each wave owns its O h-slice fully -> no Obuf reduction epilogue.
// ---------------------------------------------------------------------------
__global__ __launch_bounds__(512, 4) void attn_kernel(
    const f16* __restrict__ Qf, const f16* __restrict__ Kf,
    const f16* __restrict__ Vf,
    float* __restrict__ out)
{
    __shared__ __align__(16) f16 PL[4 * 512];    // 4 KB: P A-frags kc=0..3
    __shared__ float lred[8][16];

    const int t    = threadIdx.x;
    const int w    = t >> 6;
    const int lane = t & 63;
    const int quad = lane >> 4;
    const int lx   = lane & 15;

    // R4 CU-balanced mapping: adjacent blocks sum to 127; (i, i+256) too.
    const int j    = blockIdx.x & 255;
    const int r    = blockIdx.x >> 8;
    const int u    = j & 127;
    const int q0t  = (u & 1) ? (127 - (u >> 1)) : (u >> 1);
    const int qt   = r ? (127 - q0t) : q0t;
    const int b    = (j >> 7) + (r << 1);
    const int q0   = qt * 16;
    const int tb   = b * 128;

    half8 qa[4];
#pragma unroll
    for (int hc = 0; hc < 4; ++hc)
        qa[hc] = *(const half8*)&Qf[(((size_t)(tb + qt)) * 4 + hc) * 512 + lane * 8];

    f32x4 O = f32x4{0.f, 0.f, 0.f, 0.f};
    float lp[4] = {0.f, 0.f, 0.f, 0.f};

    const int nch = (qt >> 3) + 1;

    half8 kbA[4], vbA[4], kbB[4], vbB[4];

    // K frags for chunk c, k-tile w: Kf[(tb + c*8 + w)*4 + hc]
    // V frags for chunk c, h-tile w: Vf[(c*4 + kc)*8 + w]
    auto load_kv = [&](int c, half8* kb, half8* vb) {
        const f16* kp = &Kf[(((size_t)(tb + c * 8 + w)) * 4) * 512 + lane * 8];
#pragma unroll
        for (int hc = 0; hc < 4; ++hc) kb[hc] = *(const half8*)&kp[(size_t)hc * 512];
        const f16* vp = &Vf[(((size_t)(c * 4)) * 8 + w) * 512 + lane * 8];
#pragma unroll
        for (int kc = 0; kc < 4; ++kc) vb[kc] = *(const half8*)&vp[(size_t)kc * 8 * 512];
    };

    auto step = [&](int c, half8* kb, half8* vb, half8* kn, half8* vn) {
        if (c + 1 < nch) load_kv(c + 1, kn, vn);     // prefetch, in-flight

        // ---- QK: Sc = Q(qt) x K(k-tile w), 4 MFMA ----
        f32x4 Sc = f32x4{0.f, 0.f, 0.f, 0.f};
#pragma unroll
        for (int hc = 0; hc < 4; ++hc)
            Sc = __builtin_amdgcn_mfma_f32_16x16x32_f16(qa[hc], kb[hc], Sc, 0, 0, 0);

        // ---- mask + exp -> lp partial + P write (A-frag layout) ----
        // element (q, k): k = (w&1)*16 + lx within frag kc = w>>1
        const int sgc = c * 128 + w * 16 + lx;
        const int qp2 = (w & 1) * 2 + (lx >> 3);
#pragma unroll
        for (int reg = 0; reg < 4; ++reg) {
            const int q = quad * 4 + reg;
            float p = (sgc <= q0 + q)
                      ? __expf(Sc[reg] * 0.08838834764831845f - 10.0f)
                      : 0.f;
            lp[reg] += p;
            PL[(w >> 1) * 512 + (qp2 * 16 + q) * 8 + (lx & 7)] = (f16)p;
        }

        BAR();   // P visible to all waves

        // ---- PV: O(h-tile w) += sum_kc P[kc] x V[kc, w], 4 MFMA ----
#pragma unroll
        for (int kc = 0; kc < 4; ++kc) {
            const half8 pa = *(const half8*)&PL[kc * 512 + lane * 8];
            O = __builtin_amdgcn_mfma_f32_16x16x32_f16(pa, vb[kc], O, 0, 0, 0);
        }

        BAR();   // PL reads done; next chunk may overwrite PL
    };

    load_kv(0, kbA, vbA);
    int c = 0;
    while (c < nch) {
        step(c, kbA, vbA, kbB, vbB); ++c;
        if (c >= nch) break;
        step(c, kbB, vbB, kbA, vbA); ++c;
    }

    // ---- epilogue: l reduce (lx within quad, then across 8 waves) ----
#pragma unroll
    for (int reg = 0; reg < 4; ++reg) {
        float v = lp[reg];
        v += __shfl_xor(v, 1, 64); v += __shfl_xor(v, 2, 64);
        v += __shfl_xor(v, 4, 64); v += __shfl_xor(v, 8, 64);
        if (lx == 0) lred[w][quad * 4 + reg] = v;
    }
    __syncthreads();
#pragma unroll
    for (int reg = 0; reg < 4; ++reg) {
        const int q = quad * 4 + reg;
        float l = 0.f;
#pragma unroll
        for (int ww = 0; ww < 8; ++ww) l += lred[ww][q];
        out[((size_t)(tb + qt) * 16 + q) * 128 + w * 16 + lx] = O[reg] / l;
    }
}

extern "C" void kernel_launch(void* const* d_in, const int* in_sizes, int n_in,
                              void* d_out, int out_size, void* d_ws, size_t ws_size,
                              hipStream_t stream) {
    const float4* X  = (const float4*)d_in[0];
    const float*  WQ = (const float*)d_in[1];
    const float*  WK = (const float*)d_in[2];
    const float*  WV = (const float*)d_in[3];

    f16* Wf = (f16*)d_ws;                     // 1024 frags  1 MB
    f16* Vf = Wf + (size_t)1024 * 512;        //  512 frags  0.5 MB
    f16* Qf = Vf + (size_t)512 * 512;         // 2048 frags  2 MB
    f16* Kf = Qf + (size_t)2048 * 512;        // 2048 frags  2 MB

    cvt_w_kernel<<<dim3(16, 8, 3), 256, 0, stream>>>(WQ, WK, WV, Wf, Vf);
    proj_kernel<<<256, 1024, 0, stream>>>(X, Wf, Qf, Kf);
    attn_kernel<<<512, 512, 0, stream>>>(Qf, Kf, Vf, (float*)d_out);
}